// Round 1
// baseline (185.022 us; speedup 1.0000x reference)
//
#include <hip/hip_runtime.h>
#include <stdint.h>

// Problem constants
#define B_   8
#define S_   2047
#define L_   2048      // S+1 (CLS prepended)
#define H_   256       // HIDDEN
#define NH_  8
#define HD_  32
#define V_   32001     // VOCAB+1
#define NCH_ 64        // t-chunks per b
#define TCH_ 32        // t per chunk (NCH_*TCH_ == L_)

__device__ __forceinline__ float foldx(float a, int off) {
    return a + __shfl_xor(a, off, 64);
}
__device__ __forceinline__ float sel8(const float a[8], int j) {
    float v = a[0];
    v = (j == 1) ? a[1] : v;
    v = (j == 2) ? a[2] : v;
    v = (j == 3) ? a[3] : v;
    v = (j == 4) ? a[4] : v;
    v = (j == 5) ? a[5] : v;
    v = (j == 6) ? a[6] : v;
    v = (j == 7) ? a[7] : v;
    return v;
}

// ---------------------------------------------------------------------------
// K0 (grid 8, block per head n): y0 = emb[2]+pe[0]; q0[k] = wq[n,k,:]·y0;
// qk[n][h] = (sum_k q0[k]*wk[n,k,h]) / sqrt(32)
// ---------------------------------------------------------------------------
__global__ __launch_bounds__(256) void k0_prep(const float* __restrict__ emb,
                                               const float* __restrict__ wq,
                                               const float* __restrict__ wk,
                                               float* __restrict__ qk,
                                               float* __restrict__ y0) {
    __shared__ float y0_l[H_];
    __shared__ float q0p[HD_][8];
    __shared__ float q0_l[HD_];
    int n = blockIdx.x, tid = threadIdx.x;
    float v = emb[2 * H_ + tid] + ((tid & 1) ? 1.0f : 0.0f);  // pe[0]: sin0/cos0
    y0_l[tid] = v;
    if (n == 0) y0[tid] = v;
    __syncthreads();
    {   // q0 partials: thread = (k, part); part covers 32 h
        int k = tid >> 3, part = tid & 7;
        const float* w = wq + (n * HD_ + k) * H_ + part * 32;
        const float* yy = y0_l + part * 32;
        float acc = 0.f;
#pragma unroll
        for (int j = 0; j < 32; ++j) acc += w[j] * yy[j];
        q0p[k][part] = acc;
    }
    __syncthreads();
    if (tid < HD_) {
        float s = 0.f;
#pragma unroll
        for (int j = 0; j < 8; ++j) s += q0p[tid][j];
        q0_l[tid] = s;
    }
    __syncthreads();
    float acc = 0.f;
    for (int k = 0; k < HD_; ++k)
        acc += q0_l[k] * wk[(n * HD_ + k) * H_ + tid];
    qk[n * H_ + tid] = acc * 0.17677669529663687f;  // 1/sqrt(32)
}

// ---------------------------------------------------------------------------
// kB (grid 512 = b*64+c, 256 thr = 4 waves, wave handles 8 t):
// fused K1+K3. Per t: gather emb row + pe (y4 stays in fp32 registers),
// 8 score dots -> 17-shuffle fold -> e = exp(score) (|score| < 1, no max-sub)
// -> broadcast e_n (8 shfl) -> acc[n] += e_n * y4, es[n] += e_n.
// Cross-wave LDS reduce -> psum[bid][n][h], esum_blk[bid][n].
// ycache / Et never materialized.
// ---------------------------------------------------------------------------
__global__ __launch_bounds__(256) void kB_scores_ybar(const int* __restrict__ x,
                                                      const float* __restrict__ emb,
                                                      const float* __restrict__ qkw,
                                                      float* __restrict__ psum,
                                                      float* __restrict__ esum_blk) {
    int bid = blockIdx.x;              // b*64 + c
    int b = bid >> 6, c = bid & 63;
    int tid = threadIdx.x, lane = tid & 63, w = tid >> 6;
    int h0 = lane * 4;

    __shared__ float qk_l[NH_ * H_];       // 8 KB, staged once per block
    __shared__ float red[4][NH_ * H_];     // 32 KB cross-wave reduce
    __shared__ float es_l[4][NH_];

    for (int i = tid; i < (NH_ * H_) / 4; i += 256)
        *(float4*)&qk_l[i * 4] = *(const float4*)(qkw + i * 4);
    __syncthreads();

    float4 qr[NH_];
#pragma unroll
    for (int n = 0; n < NH_; ++n)
        qr[n] = *(const float4*)&qk_l[n * H_ + h0];

    // pe divisors for h-pairs i0=lane*2, i1=lane*2+1 (t-independent, hoisted)
    const float cdiv = 0.07195578414202881f;  // ln(10000)/128
    float div0 = __expf(-(float)(lane * 2) * cdiv);
    float div1 = __expf(-(float)(lane * 2 + 1) * cdiv);

    float4 acc[NH_];
    float es[NH_];
#pragma unroll
    for (int n = 0; n < NH_; ++n) {
        acc[n] = make_float4(0.f, 0.f, 0.f, 0.f);
        es[n] = 0.f;
    }

    int t0 = c * TCH_ + w * 8;
    int toks[8];
#pragma unroll
    for (int i = 0; i < 8; ++i) {
        int t = t0 + i;
        toks[i] = (t == 0) ? 2 : x[b * S_ + t - 1];
    }

#pragma unroll
    for (int i = 0; i < 8; ++i) {
        int t = t0 + i;
        float4 ev = *(const float4*)(emb + (size_t)toks[i] * H_ + h0);
        float a0 = (float)t * div0, a1 = (float)t * div1;
        float4 y4;
        y4.x = ev.x + __sinf(a0); y4.y = ev.y + __cosf(a0);
        y4.z = ev.z + __sinf(a1); y4.w = ev.w + __cosf(a1);

        float a[NH_];
#pragma unroll
        for (int n = 0; n < NH_; ++n)
            a[n] = qr[n].x * y4.x + qr[n].y * y4.y + qr[n].z * y4.z + qr[n].w * y4.w;

        float m4[4];
#pragma unroll
        for (int k = 0; k < 4; ++k) {
            float lo = foldx(a[k], 32), hi = foldx(a[k + 4], 32);
            m4[k] = (lane & 32) ? hi : lo;
        }
        float m2[2];
#pragma unroll
        for (int k = 0; k < 2; ++k) {
            float lo = foldx(m4[k], 16), hi = foldx(m4[k + 2], 16);
            m2[k] = (lane & 16) ? hi : lo;
        }
        float lo = foldx(m2[0], 8), hi = foldx(m2[1], 8);
        float m1 = (lane & 8) ? hi : lo;
        m1 = foldx(m1, 4); m1 = foldx(m1, 2); m1 = foldx(m1, 1);
        float e = __expf(m1);  // lane n*8.. holds head n's score sum

#pragma unroll
        for (int n = 0; n < NH_; ++n) {
            float en = __shfl(e, n * 8, 64);
            acc[n].x += en * y4.x; acc[n].y += en * y4.y;
            acc[n].z += en * y4.z; acc[n].w += en * y4.w;
            es[n] += en;
        }
    }

#pragma unroll
    for (int n = 0; n < NH_; ++n)
        *(float4*)&red[w][n * H_ + h0] = acc[n];
    if (lane < NH_) es_l[w][lane] = sel8(es, lane);
    __syncthreads();

#pragma unroll
    for (int jj = 0; jj < (NH_ * H_) / 256; ++jj) {
        int j = jj * 256 + tid;
        psum[(size_t)bid * (NH_ * H_) + j] =
            red[0][j] + red[1][j] + red[2][j] + red[3][j];
    }
    if (tid < NH_)
        esum_blk[bid * NH_ + tid] =
            es_l[0][tid] + es_l[1][tid] + es_l[2][tid] + es_l[3][tid];
}

// ---------------------------------------------------------------------------
// K4 (grid 64 = (b,n)): reduce esum + psum over 64 chunks -> ybar (normalized)
// -> wv projection -> o_g[b, n*32..+32]
// ---------------------------------------------------------------------------
__global__ __launch_bounds__(256) void k4_heads(const float* __restrict__ psum,
                                                const float* __restrict__ esum_blk,
                                                const float* __restrict__ wv,
                                                float* __restrict__ o_g) {
    int bid = blockIdx.x; int b = bid >> 3, n = bid & 7;
    int tid = threadIdx.x;
    __shared__ float inv_s;
    __shared__ float ybar_l[H_];
    __shared__ float op[HD_][8];
    if (tid < 64) {
        float v = esum_blk[(b * NCH_ + tid) * NH_ + n];
#pragma unroll
        for (int off = 32; off > 0; off >>= 1) v += __shfl_xor(v, off, 64);
        if (tid == 0) inv_s = 1.0f / v;
    }
    __syncthreads();
    {
        const float* pp = psum + ((size_t)(b * NCH_) * NH_ + n) * H_ + tid;
        float s = 0.f;
#pragma unroll 8
        for (int cc = 0; cc < NCH_; ++cc) s += pp[(size_t)cc * NH_ * H_];
        ybar_l[tid] = s * inv_s;
    }
    __syncthreads();
    {   // o[n*32+k] partial dots: thread = (k, p)
        int k = tid >> 3, p = tid & 7;
        const float* wrow = wv + (size_t)(n * HD_ + k) * H_ + p * 32;
        const float* yy = ybar_l + p * 32;
        float s = 0.f;
#pragma unroll
        for (int j = 0; j < 32; ++j) s += wrow[j] * yy[j];
        op[k][p] = s;
    }
    __syncthreads();
    if (tid < HD_) {
        float s = 0.f;
#pragma unroll
        for (int p = 0; p < 8; ++p) s += op[tid][p];
        o_g[b * (NH_ * HD_) + n * HD_ + tid] = s;
    }
}

// ---------------------------------------------------------------------------
// K4b (grid 8): z[b,i] = wo[i,:]·o[b,:] + 2*y0[i]
// ---------------------------------------------------------------------------
__global__ __launch_bounds__(256) void k4b_z(const float* __restrict__ o_g,
                                             const float* __restrict__ wo,
                                             const float* __restrict__ y0,
                                             float* __restrict__ z) {
    int b = blockIdx.x, tid = threadIdx.x;
    __shared__ float o_l[NH_ * HD_];
    o_l[tid] = o_g[b * (NH_ * HD_) + tid];
    __syncthreads();
    const float* wrow = wo + (size_t)tid * (NH_ * HD_);
    float s = 0.f;
#pragma unroll 16
    for (int j4 = 0; j4 < (NH_ * HD_) / 4; ++j4) {
        float4 w4 = *(const float4*)(wrow + j4 * 4);
        s += w4.x * o_l[j4 * 4] + w4.y * o_l[j4 * 4 + 1]
           + w4.z * o_l[j4 * 4 + 2] + w4.w * o_l[j4 * 4 + 3];
    }
    z[b * H_ + tid] = s + 2.0f * y0[tid];
}

// ---------------------------------------------------------------------------
// K5 (grid 501): out[b,v] = z[b,:]·wu[v,:]. 16-lane groups own 16-h spans;
// 4 rows per pass per wave -> 8 shuffles/row.
// ---------------------------------------------------------------------------
__global__ __launch_bounds__(256) void k5_out(const float* __restrict__ z,
                                              const float* __restrict__ wu,
                                              float* __restrict__ out) {
    int tid = threadIdx.x, lane = tid & 63, w = tid >> 6;
    int m = lane & 15;
    int g = lane >> 4;
    int hb = m * 16;
    float zr[B_][16];
#pragma unroll
    for (int b = 0; b < B_; ++b)
#pragma unroll
        for (int jj = 0; jj < 4; ++jj)
            *(float4*)&zr[b][jj * 4] = *(const float4*)(z + b * H_ + hb + jj * 4);

    __shared__ float o_l[B_ * 65];
    int base = blockIdx.x * 64;
#pragma unroll
    for (int pass = 0; pass < 4; ++pass) {
        int rl = w * 16 + pass * 4 + g;
        int v = base + rl;
        int vc = (v < V_) ? v : (V_ - 1);
        const float* wr = wu + (size_t)vc * H_ + hb;
        float4 w0 = *(const float4*)(wr);
        float4 w1 = *(const float4*)(wr + 4);
        float4 w2 = *(const float4*)(wr + 8);
        float4 w3 = *(const float4*)(wr + 12);
        float acc[B_];
#pragma unroll
        for (int b = 0; b < B_; ++b) {
            acc[b] = zr[b][0] * w0.x + zr[b][1] * w0.y + zr[b][2] * w0.z + zr[b][3] * w0.w
                   + zr[b][4] * w1.x + zr[b][5] * w1.y + zr[b][6] * w1.z + zr[b][7] * w1.w
                   + zr[b][8] * w2.x + zr[b][9] * w2.y + zr[b][10] * w2.z + zr[b][11] * w2.w
                   + zr[b][12] * w3.x + zr[b][13] * w3.y + zr[b][14] * w3.z + zr[b][15] * w3.w;
        }
#pragma unroll
        for (int off = 1; off <= 8; off <<= 1) {
#pragma unroll
            for (int b = 0; b < B_; ++b) acc[b] += __shfl_xor(acc[b], off, 64);
        }
        if (m < B_) o_l[m * 65 + rl] = sel8(acc, m);
    }
    __syncthreads();
    for (int i = tid; i < B_ * 64; i += 256) {
        int b = i >> 6, vl = i & 63, v = base + vl;
        if (v < V_) out[b * V_ + v] = o_l[b * 65 + vl];
    }
}

// ---------------------------------------------------------------------------
extern "C" void kernel_launch(void* const* d_in, const int* in_sizes, int n_in,
                              void* d_out, int out_size, void* d_ws, size_t ws_size,
                              hipStream_t stream) {
    const int*   x   = (const int*)d_in[0];
    const float* emb = (const float*)d_in[1];
    const float* wq  = (const float*)d_in[2];
    const float* wk  = (const float*)d_in[3];
    const float* wv  = (const float*)d_in[4];
    const float* wo  = (const float*)d_in[5];
    const float* wu  = (const float*)d_in[6];
    float*       out = (float*)d_out;

    // ws layout (floats), ~4.1 MiB total:
    // qk[2048] | y0[256] | z[2048] | o_g[2048] | esum_blk[4096] | psum[512*8*256]
    float* qk       = (float*)d_ws;
    float* y0       = qk + NH_ * H_;
    float* z        = y0 + H_;
    float* o_g      = z + B_ * H_;
    float* esum_blk = o_g + NH_ * HD_ * B_;
    float* psum     = esum_blk + 512 * NH_;

    k0_prep       <<<8,   256, 0, stream>>>(emb, wq, wk, qk, y0);
    kB_scores_ybar<<<512, 256, 0, stream>>>(x, emb, qk, psum, esum_blk);
    k4_heads      <<<64,  256, 0, stream>>>(psum, esum_blk, wv, o_g);
    k4b_z         <<<8,   256, 0, stream>>>(o_g, wo, y0, z);
    k5_out        <<<(V_ + 63) / 64, 256, 0, stream>>>(z, wu, out);
}